// Round 3
// baseline (441.558 us; speedup 1.0000x reference)
//
#include <hip/hip_runtime.h>
#include <hip/hip_bf16.h>
#include <stdint.h>

#define BSZ   8192
#define D_IN  4096
#define D_OUT 4096
#define NM    128   // 8192/64 m-blocks
#define NK    64    // 4096/64 k-blocks

typedef __bf16 bf16x8 __attribute__((ext_vector_type(8)));
typedef float  f32x4  __attribute__((ext_vector_type(4)));
typedef unsigned short ushort_t;

__device__ __forceinline__ ushort_t f2bf(float f) {
  union { __hip_bfloat16 h; ushort_t u; } c;
  c.h = __float2bfloat16(f);
  return c.u;
}

__device__ __forceinline__ bf16x8 ld_frag(const ushort_t* p) {
  union { uint4 u; bf16x8 b; } cv;
  cv.u = *(const uint4*)p;
  return cv.b;
}

__device__ __forceinline__ void glds16(const ushort_t* g, ushort_t* l) {
  __builtin_amdgcn_global_load_lds(
      (const __attribute__((address_space(1))) unsigned int*)g,
      (__attribute__((address_space(3))) unsigned int*)l,
      16, 0, 0);
}

// ---------------------------------------------------------------------------
// Prep kernel: blocks [0,8192) do per-64x64-block mask + bf16 cast of x
// (fp64 abs-sum -> fp32 avg > 0.8, identical math to R2 -> identical mask);
// blocks [8192,12288) do the w fp32 [k][n] -> wT bf16 [n][k] tile transpose.
// Merged so the two independent passes overlap on-device.
// ---------------------------------------------------------------------------
__global__ __launch_bounds__(256) void prep_kernel(
    const float* __restrict__ x, const float* __restrict__ w,
    ushort_t* __restrict__ xb, ushort_t* __restrict__ wT,
    int* __restrict__ mask) {
  __shared__ union {
    struct { double wsum[4]; int mflag; } m;
    ushort_t t[64][65];
  } sm;

  const int bid = blockIdx.x;
  const int tid = threadIdx.x;

  if (bid < NM * NK) {
    // ---- mask + cast part ----
    const int kblk = bid & (NK - 1);
    const int mblk = bid >> 6;
    const int lane = tid & 63;
    const int wv   = tid >> 6;
    const size_t row0 = (size_t)mblk * 64;
    const int    col0 = kblk * 64;

    float4 v[4];
    double s = 0.0;
#pragma unroll
    for (int i = 0; i < 4; ++i) {
      int j = i * 256 + tid;
      int r = j >> 4;
      int c = (j & 15) * 4;
      v[i] = *(const float4*)(x + (row0 + r) * D_IN + col0 + c);
      s += (double)fabsf(v[i].x) + (double)fabsf(v[i].y) +
           (double)fabsf(v[i].z) + (double)fabsf(v[i].w);
    }

#pragma unroll
    for (int off = 32; off > 0; off >>= 1) {
      union { double d; int i2[2]; } u;
      u.d = s;
      u.i2[0] = __shfl_xor(u.i2[0], off, 64);
      u.i2[1] = __shfl_xor(u.i2[1], off, 64);
      s += u.d;
    }

    if (lane == 0) sm.m.wsum[wv] = s;
    __syncthreads();
    if (tid == 0) {
      double tot = sm.m.wsum[0] + sm.m.wsum[1] + sm.m.wsum[2] + sm.m.wsum[3];
      float avg = (float)(tot * (1.0 / 4096.0));
      int m = (avg > 0.8f) ? 1 : 0;
      sm.m.mflag = m;
      mask[mblk * NK + kblk] = m;
    }
    __syncthreads();

    if (sm.m.mflag) {
#pragma unroll
      for (int i = 0; i < 4; ++i) {
        int j = i * 256 + tid;
        int r = j >> 4;
        int c = (j & 15) * 4;
        ushort4 o = make_ushort4(f2bf(v[i].x), f2bf(v[i].y),
                                 f2bf(v[i].z), f2bf(v[i].w));
        *(ushort4*)(xb + (row0 + r) * D_IN + col0 + c) = o;
      }
    }
  } else {
    // ---- weight transpose part ----
    const int tt = bid - NM * NK;
    const int ntile = tt & 63;
    const int ktile = tt >> 6;
    const int k0 = ktile * 64, n0 = ntile * 64;

#pragma unroll
    for (int i = 0; i < 4; ++i) {
      int j = i * 256 + tid;
      int r = j >> 4;              // k within tile
      int c = (j & 15) * 4;        // n within tile
      float4 v = *(const float4*)(w + (size_t)(k0 + r) * D_OUT + n0 + c);
      sm.t[r][c + 0] = f2bf(v.x);
      sm.t[r][c + 1] = f2bf(v.y);
      sm.t[r][c + 2] = f2bf(v.z);
      sm.t[r][c + 3] = f2bf(v.w);
    }
    __syncthreads();
#pragma unroll
    for (int i = 0; i < 4; ++i) {
      int j = i * 256 + tid;
      int r = j >> 4;              // n within tile
      int c = (j & 15) * 4;        // k within tile
      ushort4 o = make_ushort4(sm.t[c + 0][r], sm.t[c + 1][r],
                               sm.t[c + 2][r], sm.t[c + 3][r]);
      *(ushort4*)(wT + (size_t)(n0 + r) * D_IN + k0 + c) = o;
    }
  }
}

// ---------------------------------------------------------------------------
// Kernel C: block-sparse bf16 MFMA GEMM.
// WG tile: M=64 (mask granularity), N=512, BK=64. 4 waves; wave wv computes
// 64x128 (4x8 frags of 16x16x32) -> 42.7 FLOP per LDS byte read (vs 32 at
// 64x64), dropping LDS-read demand to ~93 B/cyc/CU (~= measured ds_read_b128
// ceiling) and halving barrier count per FLOP. B-staging demand is 1/M and
// fixed by the mask granularity.
//
// XOR-swizzled LDS (R2): lane l stages global chunk (l&7)^(l>>3) of its row;
// readback chunk (c*4+q)^(row&7) -> conflict-free (verified: conflicts = 0).
// ---------------------------------------------------------------------------
__global__ __launch_bounds__(256, 2) void bsp_gemm_kernel(
    const ushort_t* __restrict__ xb, const ushort_t* __restrict__ wT,
    const int* __restrict__ mask, float* __restrict__ out) {
  const int mblk  = blockIdx.x;  // 0..127
  const int ntile = blockIdx.y;  // 0..7
  const int tid   = threadIdx.x;
  const int lane  = tid & 63;
  const int wv    = tid >> 6;    // wave 0..3
  const int m0 = mblk * 64;
  const int n0 = ntile * 512;

  __shared__ ushort_t As[64 * 64];    //  8 KB
  __shared__ ushort_t Bs[512 * 64];   // 64 KB
  __shared__ int nact;
  __shared__ unsigned char klist[64];

  const int* mrow = mask + mblk * NK;
  if (tid == 0) {
    int n = 0;
#pragma unroll
    for (int kb = 0; kb < NK; ++kb) {
      if (mrow[kb] != 0) klist[n++] = (unsigned char)kb;
    }
    nact = n;
  }
  __syncthreads();
  const int na = nact;

  f32x4 acc[4][8] = {};

  const int lr  = lane >> 3;                       // 0..7 row within 8-row group
  const int lcs = ((lane & 7) ^ (lane >> 3)) * 8;  // swizzled staging chunk
  const int q   = lane >> 4;                       // quad 0..3
  const int l15 = lane & 15;
  const int sx  = l15 & 7;                         // readback swizzle phase

  for (int ki = 0; ki < na; ++ki) {
    const int kb = klist[ki];
    const int k0 = kb * 64;

    // stage A: 64x64 bf16, 2 glds/wave
#pragma unroll
    for (int t = 0; t < 2; ++t) {
      int rb = wv * 16 + t * 8;
      glds16(xb + (size_t)(m0 + rb + lr) * D_IN + k0 + lcs, &As[rb * 64]);
    }
    // stage B: 512x64 bf16, 16 glds/wave
#pragma unroll
    for (int t = 0; t < 16; ++t) {
      int rb = wv * 128 + t * 8;
      glds16(wT + (size_t)(n0 + rb + lr) * D_IN + k0 + lcs, &Bs[rb * 64]);
    }
    __syncthreads();

#pragma unroll
    for (int c = 0; c < 2; ++c) {
      const int sw = ((c * 4 + q) ^ sx) * 8;
      bf16x8 a[4];
#pragma unroll
      for (int i = 0; i < 4; ++i)
        a[i] = ld_frag(&As[(i * 16 + l15) * 64 + sw]);
#pragma unroll
      for (int j = 0; j < 8; ++j) {
        bf16x8 b = ld_frag(&Bs[(wv * 128 + j * 16 + l15) * 64 + sw]);
#pragma unroll
        for (int i = 0; i < 4; ++i)
          acc[i][j] = __builtin_amdgcn_mfma_f32_16x16x32_bf16(
              a[i], b, acc[i][j], 0, 0, 0);
      }
    }
    __syncthreads();
  }

  // epilogue: C/D layout col=lane&15, row=quad*4+reg
#pragma unroll
  for (int i = 0; i < 4; ++i) {
#pragma unroll
    for (int j = 0; j < 8; ++j) {
#pragma unroll
      for (int r = 0; r < 4; ++r) {
        int row = m0 + i * 16 + q * 4 + r;
        int col = n0 + wv * 128 + j * 16 + l15;
        out[(size_t)row * D_OUT + col] = acc[i][j][r];
      }
    }
  }
}

// ---------------------------------------------------------------------------
extern "C" void kernel_launch(void* const* d_in, const int* in_sizes, int n_in,
                              void* d_out, int out_size, void* d_ws, size_t ws_size,
                              hipStream_t stream) {
  const float* x = (const float*)d_in[0];
  const float* w = (const float*)d_in[1];

  // workspace layout: x_bf16 (64 MB) | wT_bf16 (32 MB) | mask (32 KB)
  ushort_t* xb  = (ushort_t*)d_ws;
  ushort_t* wT  = (ushort_t*)((char*)d_ws + (size_t)BSZ * D_IN * 2);
  int*      msk = (int*)((char*)d_ws + (size_t)BSZ * D_IN * 2 + (size_t)D_IN * D_OUT * 2);
  float*    out = (float*)d_out;

  hipLaunchKernelGGL(prep_kernel, dim3(NM * NK + 64 * 64), dim3(256), 0, stream,
                     x, w, xb, wT, msk);
  hipLaunchKernelGGL(bsp_gemm_kernel, dim3(NM, D_OUT / 512), dim3(256), 0, stream,
                     xb, wT, msk, out);
}